// Round 2
// baseline (820.253 us; speedup 1.0000x reference)
//
#include <hip/hip_runtime.h>

// UltraSparseMoE: B=2,S=1024,D=1024,H=4096,E=8,K=2,NS=1. fp32 in/out.
// R4: counted-vmcnt software pipeline (T4): raw s_barrier + asm s_waitcnt vmcnt(N),
// never draining to 0 in the main loop. gemm1: 3-deep LDS ring (72KB), gemm2:
// 4-deep ring (64KB). Loads stay in flight across barriers.

#define TD 2048
#define DD 1024
#define HH 4096
#define NEXP 8

typedef _Float16 f16x8 __attribute__((ext_vector_type(8)));
typedef _Float16 f16x4 __attribute__((ext_vector_type(4)));
typedef float f32x4 __attribute__((ext_vector_type(4)));

// ---- workspace layout (bytes) ----
#define WS_COUNTS   0
#define WS_CURS     64
#define WS_HBASE    128
#define WS_TOKLIST  256                       // int[8*2048] -> ends 65792
#define WS_TOPI     65792                     // int[4096]
#define WS_TOPW     82176                     // float[4096]
#define WS_POS      98560                     // int[4096]
#define WS_XH       131072                    // fp16 x [2048][1024] = 4 MB
#define WS_H        4325376                   // fp16 h [7168][4096] = 58.7 MB
#define WS_WT       63045632                  // fp16 transposed weights, 18 slots x 8 MB
#define WTSLOT      ((size_t)DD * HH)         // 4M halfs = 8 MB
// y0/y1 (fp16 [7168][1024] = 14.7 MB each) live in dead wt slots 9-12 during gemm2.

// ---- async global->LDS, width 16 ----
typedef __attribute__((address_space(3))) void lds_void;
typedef const __attribute__((address_space(1))) void gbl_void;
__device__ __forceinline__ void gld16(void* l, const void* g) {
  __builtin_amdgcn_global_load_lds((gbl_void*)g, (lds_void*)l, 16, 0, 0);
}

// swizzled fragment read: tile is [128 rows][32 halfs], granule q stored at q^((row>>1)&3)
__device__ __forceinline__ f16x8 frag_ld(const _Float16* tile, int r, int qsel) {
  int q = qsel ^ ((r >> 1) & 3);
  return *(const f16x8*)((const char*)tile + r * 64 + q * 16);
}

// ---------------- x -> fp16 ----------------
__global__ __launch_bounds__(256) void k_xh(const float* __restrict__ x, _Float16* __restrict__ xh) {
  int i = (blockIdx.x * 256 + threadIdx.x) * 8;
  float4 a = *(const float4*)(x + i), b = *(const float4*)(x + i + 4);
  f16x8 v = {(_Float16)a.x, (_Float16)a.y, (_Float16)a.z, (_Float16)a.w,
             (_Float16)b.x, (_Float16)b.y, (_Float16)b.z, (_Float16)b.w};
  *(f16x8*)(xh + i) = v;
}

// ---------------- router ----------------
__global__ __launch_bounds__(256) void k_router(const float* __restrict__ x,
    const float* __restrict__ rw, float* __restrict__ logits,
    int* __restrict__ topi, float* __restrict__ topw, int* __restrict__ counts) {
  int wv = threadIdx.x >> 6, lane = threadIdx.x & 63;
  int t = blockIdx.x * 4 + wv;
  const float* xt = x + (size_t)t * DD;
  float lg[NEXP];
#pragma unroll
  for (int e = 0; e < NEXP; ++e) {
    const float* we = rw + e * DD;
    float acc = 0.f;
#pragma unroll
    for (int j = 0; j < DD / 64; ++j) acc += xt[j * 64 + lane] * we[j * 64 + lane];
#pragma unroll
    for (int off = 32; off; off >>= 1) acc += __shfl_xor(acc, off);
    lg[e] = acc;
  }
  if (lane == 0) {
    float m = lg[0];
#pragma unroll
    for (int e = 1; e < NEXP; ++e) m = fmaxf(m, lg[e]);
    float p[NEXP];
#pragma unroll
    for (int e = 0; e < NEXP; ++e) p[e] = __expf(lg[e] - m);
    int i0 = 0; float p0 = p[0];
#pragma unroll
    for (int e = 1; e < NEXP; ++e) if (p[e] > p0) { p0 = p[e]; i0 = e; }
    int i1 = -1; float p1 = -1.f;
#pragma unroll
    for (int e = 0; e < NEXP; ++e) if (e != i0 && p[e] > p1) { p1 = p[e]; i1 = e; }
    float wsum = p0 + p1;
#pragma unroll
    for (int e = 0; e < NEXP; ++e) logits[t * NEXP + e] = lg[e];
    topi[t * 2] = i0; topi[t * 2 + 1] = i1;
    topw[t * 2] = p0 / wsum; topw[t * 2 + 1] = p1 / wsum;
    atomicAdd(&counts[i0], 1); atomicAdd(&counts[i1], 1);
  }
}

__global__ void k_offsets(const int* __restrict__ counts, int* __restrict__ hbase) {
  if (threadIdx.x == 0) {
    int base = TD;  // shared-expert rows occupy h[0..2047]
    for (int e = 0; e < NEXP; ++e) { hbase[e] = base; base += (counts[e] + 127) & ~127; }
  }
}

__global__ void k_scatter(const int* __restrict__ topi, int* __restrict__ curs,
                          int* __restrict__ tokl, int* __restrict__ posarr) {
  int tid = blockIdx.x * 256 + threadIdx.x;
  if (tid >= TD * 2) return;
  int e = topi[tid];
  int pos = atomicAdd(&curs[e], 1);
  tokl[e * TD + pos] = tid >> 1;
  posarr[tid] = pos;
}

// ---------------- transpose + fp32->fp16 (128-row x 64-col tiles) ----------------
__device__ __forceinline__ void transpose_tile(const float* __restrict__ src,
    _Float16* __restrict__ dst, int R, int C, int r0, int c0) {
  __shared__ _Float16 tile[128][68];   // row stride 136B: 8B-aligned f16x4 stores
  int t = threadIdx.x;
#pragma unroll
  for (int i = 0; i < 8; ++i) {
    int r = (t >> 4) + i * 16;         // 0..127
    int c = (t & 15) * 4;              // 0..60
    float4 v = *(const float4*)(src + (size_t)(r0 + r) * C + c0 + c);
    *(f16x4*)&tile[r][c] = (f16x4){(_Float16)v.x, (_Float16)v.y, (_Float16)v.z, (_Float16)v.w};
  }
  __syncthreads();
#pragma unroll
  for (int i = 0; i < 4; ++i) {
    int cc = (t >> 4) + i * 16;        // 0..63
    int rr = (t & 15) * 8;             // 0..120; 16 lanes -> 256B contiguous run
    f16x8 hv;
#pragma unroll
    for (int j = 0; j < 8; ++j) hv[j] = tile[rr + j][cc];
    *(f16x8*)(dst + (size_t)(c0 + cc) * R + r0 + rr) = hv;
  }
}

// phase 1: [1024][4096] mats: slot 0=sw1, 1=sw2, 2..9=w1[e], 10..17=w2[e]
__global__ __launch_bounds__(256) void k_tr1(const float* __restrict__ sw1, const float* __restrict__ sw2,
    const float* __restrict__ w1, const float* __restrict__ w2, _Float16* __restrict__ wt) {
  int id = blockIdx.y;
  const float* src = (id == 0) ? sw1 : (id == 1) ? sw2
                   : (id < 10) ? w1 + (size_t)(id - 2) * DD * HH
                               : w2 + (size_t)(id - 10) * DD * HH;
  _Float16* dst = wt + (size_t)id * WTSLOT;
  transpose_tile(src, dst, DD, HH, (blockIdx.x >> 6) * 128, (blockIdx.x & 63) * 64);
}

// phase 2 (after gemm1): [4096][1024] mats: 0=sw3, 1..8=w3[e]
__global__ __launch_bounds__(256) void k_tr2(const float* __restrict__ sw3,
    const float* __restrict__ w3, _Float16* __restrict__ wt) {
  int id = blockIdx.y;
  const float* src = (id == 0) ? sw3 : w3 + (size_t)(id - 1) * HH * DD;
  _Float16* dst = wt + (size_t)id * WTSLOT;
  transpose_tile(src, dst, HH, DD, (blockIdx.x >> 4) * 128, (blockIdx.x & 15) * 64);
}

// ---------------- GEMM1: h = silu(x@W1) * (x@W2), fp16 out ----------------
// 3-deep counted-vmcnt pipeline: stage tile t+2, wait vmcnt(12) (tiles t+1,t+2
// stay in flight across the barriers), compute tile t.
__global__ __launch_bounds__(256, 2) void k_gemm1(
    const _Float16* __restrict__ xh, const _Float16* __restrict__ wt,
    const int* __restrict__ counts, const int* __restrict__ hbase,
    const int* __restrict__ tok_list, _Float16* __restrict__ h) {
  __shared__ _Float16 lA[3][128 * 32];
  __shared__ _Float16 lB1[3][128 * 32];
  __shared__ _Float16 lB2[3][128 * 32];
  __shared__ int stok[128];

  int slot = blockIdx.y;
  const _Float16 *w1t, *w2t;
  int hrow0;
  if (slot < 16) {
    w1t = wt; w2t = wt + WTSLOT; hrow0 = slot * 128;
  } else {
    int e = (slot - 16) >> 4, rt = (slot - 16) & 15;
    if (rt * 128 >= counts[e]) return;
    w1t = wt + (size_t)(2 + e) * WTSLOT;
    w2t = wt + (size_t)(10 + e) * WTSLOT;
    hrow0 = hbase[e] + rt * 128;
  }
  if (threadIdx.x < 128) {
    int tok = (slot < 16) ? (hrow0 + threadIdx.x)
                          : tok_list[((slot - 16) >> 4) * TD + ((slot - 16) & 15) * 128 + threadIdx.x];
    stok[threadIdx.x] = tok;
  }
  __syncthreads();

  int n0 = blockIdx.x * 128;
  int wv = threadIdx.x >> 6, lane = threadIdx.x & 63;
  int wm = (wv & 1) * 64, wn = (wv >> 1) * 64;
  int qsel = lane >> 4;
  int r15 = lane & 15;

  // per-lane staging sources: wave wv issues granule-rows j = 2wv, 2wv+1 of each tile
  const _Float16 *gA[2], *gB1[2], *gB2[2];
  int ldsoff[2];
#pragma unroll
  for (int jj = 0; jj < 2; ++jj) {
    int j = wv * 2 + jj;
    int n = j * 16 + (lane >> 2);
    int q = (lane & 3) ^ ((n >> 1) & 3);
    gA[jj]  = xh + (size_t)stok[n] * DD + q * 8;
    gB1[jj] = w1t + (size_t)(n0 + n) * DD + q * 8;
    gB2[jj] = w2t + (size_t)(n0 + n) * DD + q * 8;
    ldsoff[jj] = j * 1024 + lane * 16;
  }

#define G1_STAGE(buf, kk)                                   \
  do {                                                      \
    _Pragma("unroll")                                       \
    for (int jj = 0; jj < 2; ++jj) {                        \
      gld16((char*)lA[buf] + ldsoff[jj], gA[jj] + (kk));    \
      gld16((char*)lB1[buf] + ldsoff[jj], gB1[jj] + (kk));  \
      gld16((char*)lB2[buf] + ldsoff[jj], gB2[jj] + (kk));  \
    }                                                       \
  } while (0)

  f32x4 acc1[4][4] = {}; f32x4 acc2[4][4] = {};

  auto compute = [&](int b) {
    f16x8 af[4];
#pragma unroll
    for (int mi = 0; mi < 4; ++mi) af[mi] = frag_ld(lA[b], wm + mi * 16 + r15, qsel);
#pragma unroll
    for (int ni = 0; ni < 4; ++ni) {
      f16x8 b1 = frag_ld(lB1[b], wn + ni * 16 + r15, qsel);
      f16x8 b2 = frag_ld(lB2[b], wn + ni * 16 + r15, qsel);
#pragma unroll
      for (int mi = 0; mi < 4; ++mi) {
        acc1[mi][ni] = __builtin_amdgcn_mfma_f32_16x16x32_f16(af[mi], b1, acc1[mi][ni], 0, 0, 0);
        acc2[mi][ni] = __builtin_amdgcn_mfma_f32_16x16x32_f16(af[mi], b2, acc2[mi][ni], 0, 0, 0);
      }
    }
  };

  // prologue: stage tiles 0,1
  G1_STAGE(0, 0);
  G1_STAGE(1, 32);

  int cb = 0, wb = 2;
  for (int t = 0; t < DD / 32 - 2; ++t) {          // t = 0..29
    G1_STAGE(wb, (t + 2) * 32);
    asm volatile("s_waitcnt vmcnt(12)" ::: "memory");  // tile t landed; t+1,t+2 in flight
    __builtin_amdgcn_s_barrier();
    compute(cb);
    asm volatile("s_waitcnt lgkmcnt(0)" ::: "memory"); // LDS reads done -> safe overwrite
    __builtin_amdgcn_s_barrier();
    cb = (cb == 2) ? 0 : cb + 1;
    wb = (wb == 2) ? 0 : wb + 1;
  }
  // t = 30: nothing to stage, tile 31 still in flight
  asm volatile("s_waitcnt vmcnt(6)" ::: "memory");
  __builtin_amdgcn_s_barrier();
  compute(cb);
  asm volatile("s_waitcnt lgkmcnt(0)" ::: "memory");
  __builtin_amdgcn_s_barrier();
  cb = (cb == 2) ? 0 : cb + 1;
  // t = 31
  asm volatile("s_waitcnt vmcnt(0)" ::: "memory");
  __builtin_amdgcn_s_barrier();
  compute(cb);
#undef G1_STAGE

#pragma unroll
  for (int mi = 0; mi < 4; ++mi)
#pragma unroll
    for (int ni = 0; ni < 4; ++ni)
#pragma unroll
      for (int i = 0; i < 4; ++i) {
        int r = wm + mi * 16 + (lane >> 4) * 4 + i;
        int c = wn + ni * 16 + (lane & 15);
        float a = acc1[mi][ni][i], b = acc2[mi][ni][i];
        h[(size_t)(hrow0 + r) * HH + n0 + c] = (_Float16)((a / (1.f + __expf(-a))) * b);
      }
}

// ---------------- GEMM2: y_z = h @ W3 (split-K partials, fp16, no atomics) ----------------
// 4-deep counted-vmcnt pipeline (16 MFMA/step -> deeper prefetch).
__global__ __launch_bounds__(256, 2) void k_gemm2(
    const _Float16* __restrict__ h, const _Float16* __restrict__ wt,
    const int* __restrict__ counts, const int* __restrict__ hbase,
    _Float16* __restrict__ y0, _Float16* __restrict__ y1) {
  __shared__ _Float16 lA[4][128 * 32];
  __shared__ _Float16 lB[4][128 * 32];

  int slot = blockIdx.y;
  const _Float16* w3t;
  int hrow0;
  if (slot < 16) {
    w3t = wt; hrow0 = slot * 128;
  } else {
    int e = (slot - 16) >> 4, rt = (slot - 16) & 15;
    if (rt * 128 >= counts[e]) return;
    w3t = wt + (size_t)(1 + e) * WTSLOT;
    hrow0 = hbase[e] + rt * 128;
  }
  _Float16* y = blockIdx.z ? y1 : y0;
  int kz0 = blockIdx.z * (HH / 2);

  int n0 = blockIdx.x * 128;
  int wv = threadIdx.x >> 6, lane = threadIdx.x & 63;
  int wm = (wv & 1) * 64, wn = (wv >> 1) * 64;
  int qsel = lane >> 4;
  int r15 = lane & 15;

  const _Float16 *gA[2], *gB[2];
  int ldsoff[2];
#pragma unroll
  for (int jj = 0; jj < 2; ++jj) {
    int j = wv * 2 + jj;
    int n = j * 16 + (lane >> 2);
    int q = (lane & 3) ^ ((n >> 1) & 3);
    gA[jj] = h   + (size_t)(hrow0 + n) * HH + kz0 + q * 8;
    gB[jj] = w3t + (size_t)(n0 + n)   * HH + kz0 + q * 8;
    ldsoff[jj] = j * 1024 + lane * 16;
  }

#define G2_STAGE(buf, kk)                                 \
  do {                                                    \
    _Pragma("unroll")                                     \
    for (int jj = 0; jj < 2; ++jj) {                      \
      gld16((char*)lA[buf] + ldsoff[jj], gA[jj] + (kk));  \
      gld16((char*)lB[buf] + ldsoff[jj], gB[jj] + (kk));  \
    }                                                     \
  } while (0)

  f32x4 acc[4][4] = {};

  auto compute = [&](int b) {
    f16x8 af[4];
#pragma unroll
    for (int mi = 0; mi < 4; ++mi) af[mi] = frag_ld(lA[b], wm + mi * 16 + r15, qsel);
#pragma unroll
    for (int ni = 0; ni < 4; ++ni) {
      f16x8 bf = frag_ld(lB[b], wn + ni * 16 + r15, qsel);
#pragma unroll
      for (int mi = 0; mi < 4; ++mi)
        acc[mi][ni] = __builtin_amdgcn_mfma_f32_16x16x32_f16(af[mi], bf, acc[mi][ni], 0, 0, 0);
    }
  };

  // prologue: stage tiles 0,1,2
  G2_STAGE(0, 0);
  G2_STAGE(1, 32);
  G2_STAGE(2, 64);

  const int NT = (HH / 2) / 32;                    // 64
  for (int t = 0; t < NT - 3; ++t) {               // t = 0..60
    G2_STAGE((t + 3) & 3, (t + 3) * 32);
    asm volatile("s_waitcnt vmcnt(12)" ::: "memory");  // tile t landed; t+1..t+3 in flight
    __builtin_amdgcn_s_barrier();
    compute(t & 3);
    asm volatile("s_waitcnt lgkmcnt(0)" ::: "memory");
    __builtin_amdgcn_s_barrier();
  }
  // t = 61
  asm volatile("s_waitcnt vmcnt(8)" ::: "memory");
  __builtin_amdgcn_s_barrier();
  compute(61 & 3);
  asm volatile("s_waitcnt lgkmcnt(0)" ::: "memory");
  __builtin_amdgcn_s_barrier();
  // t = 62
  asm volatile("s_waitcnt vmcnt(4)" ::: "memory");
  __builtin_amdgcn_s_barrier();
  compute(62 & 3);
  asm volatile("s_waitcnt lgkmcnt(0)" ::: "memory");
  __builtin_amdgcn_s_barrier();
  // t = 63
  asm volatile("s_waitcnt vmcnt(0)" ::: "memory");
  __builtin_amdgcn_s_barrier();
  compute(63 & 3);
#undef G2_STAGE

#pragma unroll
  for (int mi = 0; mi < 4; ++mi)
#pragma unroll
    for (int ni = 0; ni < 4; ++ni)
#pragma unroll
      for (int i = 0; i < 4; ++i) {
        int r = wm + mi * 16 + (lane >> 4) * 4 + i;
        int c = wn + ni * 16 + (lane & 15);
        y[(size_t)(hrow0 + r) * DD + n0 + c] = (_Float16)acc[mi][ni][i];
      }
}

// ---------------- combine: out[t] = y_sh[t] + w0*y[r0] + w1*y[r1] ----------------
__global__ __launch_bounds__(256) void k_combine(
    const _Float16* __restrict__ y0, const _Float16* __restrict__ y1,
    const int* __restrict__ topi, const float* __restrict__ topw,
    const int* __restrict__ posarr, const int* __restrict__ hbase,
    float* __restrict__ out) {
  int t = blockIdx.x;
  int c = threadIdx.x * 4;
  int e0 = topi[2 * t], e1 = topi[2 * t + 1];
  float w0 = topw[2 * t], w1 = topw[2 * t + 1];
  size_t rs = (size_t)t * DD + c;
  size_t r0 = (size_t)(hbase[e0] + posarr[2 * t]) * DD + c;
  size_t r1 = (size_t)(hbase[e1] + posarr[2 * t + 1]) * DD + c;
  f16x4 s0 = *(const f16x4*)(y0 + rs), s1 = *(const f16x4*)(y1 + rs);
  f16x4 a0 = *(const f16x4*)(y0 + r0), a1 = *(const f16x4*)(y1 + r0);
  f16x4 b0 = *(const f16x4*)(y0 + r1), b1 = *(const f16x4*)(y1 + r1);
  float4 o;
  float* op = &o.x;
#pragma unroll
  for (int i = 0; i < 4; ++i)
    op[i] = (float)s0[i] + (float)s1[i] + w0 * ((float)a0[i] + (float)a1[i])
          + w1 * ((float)b0[i] + (float)b1[i]);
  *(float4*)(out + rs) = o;
}

// ---------------- launcher ----------------
extern "C" void kernel_launch(void* const* d_in, const int* in_sizes, int n_in,
                              void* d_out, int out_size, void* d_ws, size_t ws_size,
                              hipStream_t stream) {
  const float* x   = (const float*)d_in[0];
  const float* sw1 = (const float*)d_in[1];
  const float* sw2 = (const float*)d_in[2];
  const float* sw3 = (const float*)d_in[3];
  const float* w1  = (const float*)d_in[4];
  const float* w2  = (const float*)d_in[5];
  const float* w3  = (const float*)d_in[6];
  const float* rw  = (const float*)d_in[7];
  float* out = (float*)d_out;
  char* ws = (char*)d_ws;

  int*   counts = (int*)(ws + WS_COUNTS);
  int*   curs   = (int*)(ws + WS_CURS);
  int*   hbase  = (int*)(ws + WS_HBASE);
  int*   tokl   = (int*)(ws + WS_TOKLIST);
  int*   topi   = (int*)(ws + WS_TOPI);
  float* topw   = (float*)(ws + WS_TOPW);
  int*   posarr = (int*)(ws + WS_POS);
  _Float16* xh   = (_Float16*)(ws + WS_XH);
  _Float16* hbuf = (_Float16*)(ws + WS_H);
  _Float16* wt   = (_Float16*)(ws + WS_WT);
  _Float16* ybuf0 = wt + 9 * WTSLOT;   // dead w1t-expert slots during gemm2
  _Float16* ybuf1 = wt + 11 * WTSLOT;

  hipMemsetAsync(ws, 0, 65792, stream);  // counts/curs + tok lists (pad-token safety)

  k_xh<<<TD * DD / 2048, 256, 0, stream>>>(x, xh);
  k_router<<<TD / 4, 256, 0, stream>>>(x, rw, out + (size_t)TD * DD, topi, topw, counts);
  k_offsets<<<1, 64, 0, stream>>>(counts, hbase);
  k_scatter<<<16, 256, 0, stream>>>(topi, curs, tokl, posarr);

  k_tr1<<<dim3(512, 18), 256, 0, stream>>>(sw1, sw2, w1, w2, wt);
  k_gemm1<<<dim3(HH / 128, 144), 256, 0, stream>>>(xh, wt, counts, hbase, tokl, hbuf);
  k_tr2<<<dim3(512, 9), 256, 0, stream>>>(sw3, w3, wt);
  k_gemm2<<<dim3(DD / 128, 144, 2), 256, 0, stream>>>(hbuf, wt, counts, hbase, ybuf0, ybuf1);
  k_combine<<<TD, 256, 0, stream>>>(ybuf0, ybuf1, topi, topw, posarr, hbase, out);
}

// Round 4
// 802.952 us; speedup vs baseline: 1.0215x; 1.0215x over previous
//
#include <hip/hip_runtime.h>

// UltraSparseMoE: B=2,S=1024,D=1024,H=4096,E=8,K=2,NS=1. fp32 in/out.
// R5 (resubmit after infra failure): gemm2 K-step 32->64 (two [128][32]
// subtiles per buffer, 32 MFMA per barrier-pair = gemm1 parity), 2-deep
// counted-vmcnt ring (64KB LDS, 2 blocks/CU). gemm1 and all other kernels
// byte-identical to R4 so Delta(total) isolates gemm2.

#define TD 2048
#define DD 1024
#define HH 4096
#define NEXP 8

typedef _Float16 f16x8 __attribute__((ext_vector_type(8)));
typedef _Float16 f16x4 __attribute__((ext_vector_type(4)));
typedef float f32x4 __attribute__((ext_vector_type(4)));

// ---- workspace layout (bytes) ----
#define WS_COUNTS   0
#define WS_CURS     64
#define WS_HBASE    128
#define WS_TOKLIST  256                       // int[8*2048] -> ends 65792
#define WS_TOPI     65792                     // int[4096]
#define WS_TOPW     82176                     // float[4096]
#define WS_POS      98560                     // int[4096]
#define WS_XH       131072                    // fp16 x [2048][1024] = 4 MB
#define WS_H        4325376                   // fp16 h [7168][4096] = 58.7 MB
#define WS_WT       63045632                  // fp16 transposed weights, 18 slots x 8 MB
#define WTSLOT      ((size_t)DD * HH)         // 4M halfs = 8 MB
// y0/y1 (fp16 [7168][1024] = 14.7 MB each) live in dead wt slots 9-12 during gemm2.

// ---- async global->LDS, width 16 ----
typedef __attribute__((address_space(3))) void lds_void;
typedef const __attribute__((address_space(1))) void gbl_void;
__device__ __forceinline__ void gld16(void* l, const void* g) {
  __builtin_amdgcn_global_load_lds((gbl_void*)g, (lds_void*)l, 16, 0, 0);
}

// swizzled fragment read: tile is [128 rows][32 halfs], granule q stored at q^((row>>1)&3)
__device__ __forceinline__ f16x8 frag_ld(const _Float16* tile, int r, int qsel) {
  int q = qsel ^ ((r >> 1) & 3);
  return *(const f16x8*)((const char*)tile + r * 64 + q * 16);
}

// ---------------- x -> fp16 ----------------
__global__ __launch_bounds__(256) void k_xh(const float* __restrict__ x, _Float16* __restrict__ xh) {
  int i = (blockIdx.x * 256 + threadIdx.x) * 8;
  float4 a = *(const float4*)(x + i), b = *(const float4*)(x + i + 4);
  f16x8 v = {(_Float16)a.x, (_Float16)a.y, (_Float16)a.z, (_Float16)a.w,
             (_Float16)b.x, (_Float16)b.y, (_Float16)b.z, (_Float16)b.w};
  *(f16x8*)(xh + i) = v;
}

// ---------------- router ----------------
__global__ __launch_bounds__(256) void k_router(const float* __restrict__ x,
    const float* __restrict__ rw, float* __restrict__ logits,
    int* __restrict__ topi, float* __restrict__ topw, int* __restrict__ counts) {
  int wv = threadIdx.x >> 6, lane = threadIdx.x & 63;
  int t = blockIdx.x * 4 + wv;
  const float* xt = x + (size_t)t * DD;
  float lg[NEXP];
#pragma unroll
  for (int e = 0; e < NEXP; ++e) {
    const float* we = rw + e * DD;
    float acc = 0.f;
#pragma unroll
    for (int j = 0; j < DD / 64; ++j) acc += xt[j * 64 + lane] * we[j * 64 + lane];
#pragma unroll
    for (int off = 32; off; off >>= 1) acc += __shfl_xor(acc, off);
    lg[e] = acc;
  }
  if (lane == 0) {
    float m = lg[0];
#pragma unroll
    for (int e = 1; e < NEXP; ++e) m = fmaxf(m, lg[e]);
    float p[NEXP];
#pragma unroll
    for (int e = 0; e < NEXP; ++e) p[e] = __expf(lg[e] - m);
    int i0 = 0; float p0 = p[0];
#pragma unroll
    for (int e = 1; e < NEXP; ++e) if (p[e] > p0) { p0 = p[e]; i0 = e; }
    int i1 = -1; float p1 = -1.f;
#pragma unroll
    for (int e = 0; e < NEXP; ++e) if (e != i0 && p[e] > p1) { p1 = p[e]; i1 = e; }
    float wsum = p0 + p1;
#pragma unroll
    for (int e = 0; e < NEXP; ++e) logits[t * NEXP + e] = lg[e];
    topi[t * 2] = i0; topi[t * 2 + 1] = i1;
    topw[t * 2] = p0 / wsum; topw[t * 2 + 1] = p1 / wsum;
    atomicAdd(&counts[i0], 1); atomicAdd(&counts[i1], 1);
  }
}

__global__ void k_offsets(const int* __restrict__ counts, int* __restrict__ hbase) {
  if (threadIdx.x == 0) {
    int base = TD;  // shared-expert rows occupy h[0..2047]
    for (int e = 0; e < NEXP; ++e) { hbase[e] = base; base += (counts[e] + 127) & ~127; }
  }
}

__global__ void k_scatter(const int* __restrict__ topi, int* __restrict__ curs,
                          int* __restrict__ tokl, int* __restrict__ posarr) {
  int tid = blockIdx.x * 256 + threadIdx.x;
  if (tid >= TD * 2) return;
  int e = topi[tid];
  int pos = atomicAdd(&curs[e], 1);
  tokl[e * TD + pos] = tid >> 1;
  posarr[tid] = pos;
}

// ---------------- transpose + fp32->fp16 (128-row x 64-col tiles) ----------------
__device__ __forceinline__ void transpose_tile(const float* __restrict__ src,
    _Float16* __restrict__ dst, int R, int C, int r0, int c0) {
  __shared__ _Float16 tile[128][68];   // row stride 136B: 8B-aligned f16x4 stores
  int t = threadIdx.x;
#pragma unroll
  for (int i = 0; i < 8; ++i) {
    int r = (t >> 4) + i * 16;         // 0..127
    int c = (t & 15) * 4;              // 0..60
    float4 v = *(const float4*)(src + (size_t)(r0 + r) * C + c0 + c);
    *(f16x4*)&tile[r][c] = (f16x4){(_Float16)v.x, (_Float16)v.y, (_Float16)v.z, (_Float16)v.w};
  }
  __syncthreads();
#pragma unroll
  for (int i = 0; i < 4; ++i) {
    int cc = (t >> 4) + i * 16;        // 0..63
    int rr = (t & 15) * 8;             // 0..120; 16 lanes -> 256B contiguous run
    f16x8 hv;
#pragma unroll
    for (int j = 0; j < 8; ++j) hv[j] = tile[rr + j][cc];
    *(f16x8*)(dst + (size_t)(c0 + cc) * R + r0 + rr) = hv;
  }
}

// phase 1: [1024][4096] mats: slot 0=sw1, 1=sw2, 2..9=w1[e], 10..17=w2[e]
__global__ __launch_bounds__(256) void k_tr1(const float* __restrict__ sw1, const float* __restrict__ sw2,
    const float* __restrict__ w1, const float* __restrict__ w2, _Float16* __restrict__ wt) {
  int id = blockIdx.y;
  const float* src = (id == 0) ? sw1 : (id == 1) ? sw2
                   : (id < 10) ? w1 + (size_t)(id - 2) * DD * HH
                               : w2 + (size_t)(id - 10) * DD * HH;
  _Float16* dst = wt + (size_t)id * WTSLOT;
  transpose_tile(src, dst, DD, HH, (blockIdx.x >> 6) * 128, (blockIdx.x & 63) * 64);
}

// phase 2 (after gemm1): [4096][1024] mats: 0=sw3, 1..8=w3[e]
__global__ __launch_bounds__(256) void k_tr2(const float* __restrict__ sw3,
    const float* __restrict__ w3, _Float16* __restrict__ wt) {
  int id = blockIdx.y;
  const float* src = (id == 0) ? sw3 : w3 + (size_t)(id - 1) * HH * DD;
  _Float16* dst = wt + (size_t)id * WTSLOT;
  transpose_tile(src, dst, HH, DD, (blockIdx.x >> 4) * 128, (blockIdx.x & 15) * 64);
}

// ---------------- GEMM1: h = silu(x@W1) * (x@W2), fp16 out ----------------
// 3-deep counted-vmcnt pipeline: stage tile t+2, wait vmcnt(12) (tiles t+1,t+2
// stay in flight across the barriers), compute tile t.
__global__ __launch_bounds__(256, 2) void k_gemm1(
    const _Float16* __restrict__ xh, const _Float16* __restrict__ wt,
    const int* __restrict__ counts, const int* __restrict__ hbase,
    const int* __restrict__ tok_list, _Float16* __restrict__ h) {
  __shared__ _Float16 lA[3][128 * 32];
  __shared__ _Float16 lB1[3][128 * 32];
  __shared__ _Float16 lB2[3][128 * 32];
  __shared__ int stok[128];

  int slot = blockIdx.y;
  const _Float16 *w1t, *w2t;
  int hrow0;
  if (slot < 16) {
    w1t = wt; w2t = wt + WTSLOT; hrow0 = slot * 128;
  } else {
    int e = (slot - 16) >> 4, rt = (slot - 16) & 15;
    if (rt * 128 >= counts[e]) return;
    w1t = wt + (size_t)(2 + e) * WTSLOT;
    w2t = wt + (size_t)(10 + e) * WTSLOT;
    hrow0 = hbase[e] + rt * 128;
  }
  if (threadIdx.x < 128) {
    int tok = (slot < 16) ? (hrow0 + threadIdx.x)
                          : tok_list[((slot - 16) >> 4) * TD + ((slot - 16) & 15) * 128 + threadIdx.x];
    stok[threadIdx.x] = tok;
  }
  __syncthreads();

  int n0 = blockIdx.x * 128;
  int wv = threadIdx.x >> 6, lane = threadIdx.x & 63;
  int wm = (wv & 1) * 64, wn = (wv >> 1) * 64;
  int qsel = lane >> 4;
  int r15 = lane & 15;

  // per-lane staging sources: wave wv issues granule-rows j = 2wv, 2wv+1 of each tile
  const _Float16 *gA[2], *gB1[2], *gB2[2];
  int ldsoff[2];
#pragma unroll
  for (int jj = 0; jj < 2; ++jj) {
    int j = wv * 2 + jj;
    int n = j * 16 + (lane >> 2);
    int q = (lane & 3) ^ ((n >> 1) & 3);
    gA[jj]  = xh + (size_t)stok[n] * DD + q * 8;
    gB1[jj] = w1t + (size_t)(n0 + n) * DD + q * 8;
    gB2[jj] = w2t + (size_t)(n0 + n) * DD + q * 8;
    ldsoff[jj] = j * 1024 + lane * 16;
  }

#define G1_STAGE(buf, kk)                                   \
  do {                                                      \
    _Pragma("unroll")                                       \
    for (int jj = 0; jj < 2; ++jj) {                        \
      gld16((char*)lA[buf] + ldsoff[jj], gA[jj] + (kk));    \
      gld16((char*)lB1[buf] + ldsoff[jj], gB1[jj] + (kk));  \
      gld16((char*)lB2[buf] + ldsoff[jj], gB2[jj] + (kk));  \
    }                                                       \
  } while (0)

  f32x4 acc1[4][4] = {}; f32x4 acc2[4][4] = {};

  auto compute = [&](int b) {
    f16x8 af[4];
#pragma unroll
    for (int mi = 0; mi < 4; ++mi) af[mi] = frag_ld(lA[b], wm + mi * 16 + r15, qsel);
#pragma unroll
    for (int ni = 0; ni < 4; ++ni) {
      f16x8 b1 = frag_ld(lB1[b], wn + ni * 16 + r15, qsel);
      f16x8 b2 = frag_ld(lB2[b], wn + ni * 16 + r15, qsel);
#pragma unroll
      for (int mi = 0; mi < 4; ++mi) {
        acc1[mi][ni] = __builtin_amdgcn_mfma_f32_16x16x32_f16(af[mi], b1, acc1[mi][ni], 0, 0, 0);
        acc2[mi][ni] = __builtin_amdgcn_mfma_f32_16x16x32_f16(af[mi], b2, acc2[mi][ni], 0, 0, 0);
      }
    }
  };

  // prologue: stage tiles 0,1
  G1_STAGE(0, 0);
  G1_STAGE(1, 32);

  int cb = 0, wb = 2;
  for (int t = 0; t < DD / 32 - 2; ++t) {          // t = 0..29
    G1_STAGE(wb, (t + 2) * 32);
    asm volatile("s_waitcnt vmcnt(12)" ::: "memory");  // tile t landed; t+1,t+2 in flight
    __builtin_amdgcn_s_barrier();
    compute(cb);
    asm volatile("s_waitcnt lgkmcnt(0)" ::: "memory"); // LDS reads done -> safe overwrite
    __builtin_amdgcn_s_barrier();
    cb = (cb == 2) ? 0 : cb + 1;
    wb = (wb == 2) ? 0 : wb + 1;
  }
  // t = 30: nothing to stage, tile 31 still in flight
  asm volatile("s_waitcnt vmcnt(6)" ::: "memory");
  __builtin_amdgcn_s_barrier();
  compute(cb);
  asm volatile("s_waitcnt lgkmcnt(0)" ::: "memory");
  __builtin_amdgcn_s_barrier();
  cb = (cb == 2) ? 0 : cb + 1;
  // t = 31
  asm volatile("s_waitcnt vmcnt(0)" ::: "memory");
  __builtin_amdgcn_s_barrier();
  compute(cb);
#undef G1_STAGE

#pragma unroll
  for (int mi = 0; mi < 4; ++mi)
#pragma unroll
    for (int ni = 0; ni < 4; ++ni)
#pragma unroll
      for (int i = 0; i < 4; ++i) {
        int r = wm + mi * 16 + (lane >> 4) * 4 + i;
        int c = wn + ni * 16 + (lane & 15);
        float a = acc1[mi][ni][i], b = acc2[mi][ni][i];
        h[(size_t)(hrow0 + r) * HH + n0 + c] = (_Float16)((a / (1.f + __expf(-a))) * b);
      }
}

// ---------------- GEMM2: y_z = h @ W3 (split-K partials, fp16, no atomics) ----------------
// R5: K-step 64 (two [128][32] subtiles), 2-deep counted ring: 32 MFMA per
// barrier-pair, stage t+1 while computing t, wait vmcnt(8) (next tile's 8
// loads stay in flight).
__global__ __launch_bounds__(256, 2) void k_gemm2(
    const _Float16* __restrict__ h, const _Float16* __restrict__ wt,
    const int* __restrict__ counts, const int* __restrict__ hbase,
    _Float16* __restrict__ y0, _Float16* __restrict__ y1) {
  __shared__ _Float16 lA[2][2 * 128 * 32];   // [buf][subtile s][128][32]
  __shared__ _Float16 lB[2][2 * 128 * 32];

  int slot = blockIdx.y;
  const _Float16* w3t;
  int hrow0;
  if (slot < 16) {
    w3t = wt; hrow0 = slot * 128;
  } else {
    int e = (slot - 16) >> 4, rt = (slot - 16) & 15;
    if (rt * 128 >= counts[e]) return;
    w3t = wt + (size_t)(1 + e) * WTSLOT;
    hrow0 = hbase[e] + rt * 128;
  }
  _Float16* y = blockIdx.z ? y1 : y0;
  int kz0 = blockIdx.z * (HH / 2);

  int n0 = blockIdx.x * 128;
  int wv = threadIdx.x >> 6, lane = threadIdx.x & 63;
  int wm = (wv & 1) * 64, wn = (wv >> 1) * 64;
  int qsel = lane >> 4;
  int r15 = lane & 15;

  const _Float16 *gA[2], *gB[2];
  int ldsoff[2];
#pragma unroll
  for (int jj = 0; jj < 2; ++jj) {
    int j = wv * 2 + jj;
    int n = j * 16 + (lane >> 2);
    int q = (lane & 3) ^ ((n >> 1) & 3);
    gA[jj] = h   + (size_t)(hrow0 + n) * HH + kz0 + q * 8;
    gB[jj] = w3t + (size_t)(n0 + n)   * HH + kz0 + q * 8;
    ldsoff[jj] = j * 1024 + lane * 16;
  }

  // stage one 64-wide K-tile (two 32-wide subtiles) = 8 gld16 per lane
#define G2_STAGE(buf, kk)                                                    \
  do {                                                                       \
    _Pragma("unroll")                                                        \
    for (int s = 0; s < 2; ++s) {                                            \
      _Pragma("unroll")                                                      \
      for (int jj = 0; jj < 2; ++jj) {                                       \
        gld16((char*)lA[buf] + s * 8192 + ldsoff[jj], gA[jj] + (kk) + s * 32); \
        gld16((char*)lB[buf] + s * 8192 + ldsoff[jj], gB[jj] + (kk) + s * 32); \
      }                                                                      \
    }                                                                        \
  } while (0)

  f32x4 acc[4][4] = {};

  auto compute = [&](int b) {
#pragma unroll
    for (int s = 0; s < 2; ++s) {
      const _Float16* tA = lA[b] + s * 4096;
      const _Float16* tB = lB[b] + s * 4096;
      f16x8 af[4];
#pragma unroll
      for (int mi = 0; mi < 4; ++mi) af[mi] = frag_ld(tA, wm + mi * 16 + r15, qsel);
#pragma unroll
      for (int ni = 0; ni < 4; ++ni) {
        f16x8 bf = frag_ld(tB, wn + ni * 16 + r15, qsel);
#pragma unroll
        for (int mi = 0; mi < 4; ++mi)
          acc[mi][ni] = __builtin_amdgcn_mfma_f32_16x16x32_f16(af[mi], bf, acc[mi][ni], 0, 0, 0);
      }
    }
  };

  // prologue: stage tile 0
  G2_STAGE(0, 0);

  const int NT = (HH / 2) / 64;                    // 32
  for (int t = 0; t < NT - 1; ++t) {               // t = 0..30
    G2_STAGE((t + 1) & 1, (t + 1) * 64);
    asm volatile("s_waitcnt vmcnt(8)" ::: "memory");   // tile t landed; t+1 in flight
    __builtin_amdgcn_s_barrier();
    compute(t & 1);
    asm volatile("s_waitcnt lgkmcnt(0)" ::: "memory"); // LDS reads done -> safe overwrite
    __builtin_amdgcn_s_barrier();
  }
  // t = 31
  asm volatile("s_waitcnt vmcnt(0)" ::: "memory");
  __builtin_amdgcn_s_barrier();
  compute((NT - 1) & 1);
#undef G2_STAGE

#pragma unroll
  for (int mi = 0; mi < 4; ++mi)
#pragma unroll
    for (int ni = 0; ni < 4; ++ni)
#pragma unroll
      for (int i = 0; i < 4; ++i) {
        int r = wm + mi * 16 + (lane >> 4) * 4 + i;
        int c = wn + ni * 16 + (lane & 15);
        y[(size_t)(hrow0 + r) * DD + n0 + c] = (_Float16)acc[mi][ni][i];
      }
}

// ---------------- combine: out[t] = y_sh[t] + w0*y[r0] + w1*y[r1] ----------------
__global__ __launch_bounds__(256) void k_combine(
    const _Float16* __restrict__ y0, const _Float16* __restrict__ y1,
    const int* __restrict__ topi, const float* __restrict__ topw,
    const int* __restrict__ posarr, const int* __restrict__ hbase,
    float* __restrict__ out) {
  int t = blockIdx.x;
  int c = threadIdx.x * 4;
  int e0 = topi[2 * t], e1 = topi[2 * t + 1];
  float w0 = topw[2 * t], w1 = topw[2 * t + 1];
  size_t rs = (size_t)t * DD + c;
  size_t r0 = (size_t)(hbase[e0] + posarr[2 * t]) * DD + c;
  size_t r1 = (size_t)(hbase[e1] + posarr[2 * t + 1]) * DD + c;
  f16x4 s0 = *(const f16x4*)(y0 + rs), s1 = *(const f16x4*)(y1 + rs);
  f16x4 a0 = *(const f16x4*)(y0 + r0), a1 = *(const f16x4*)(y1 + r0);
  f16x4 b0 = *(const f16x4*)(y0 + r1), b1 = *(const f16x4*)(y1 + r1);
  float4 o;
  float* op = &o.x;
#pragma unroll
  for (int i = 0; i < 4; ++i)
    op[i] = (float)s0[i] + (float)s1[i] + w0 * ((float)a0[i] + (float)a1[i])
          + w1 * ((float)b0[i] + (float)b1[i]);
  *(float4*)(out + rs) = o;
}

// ---------------- launcher ----------------
extern "C" void kernel_launch(void* const* d_in, const int* in_sizes, int n_in,
                              void* d_out, int out_size, void* d_ws, size_t ws_size,
                              hipStream_t stream) {
  const float* x   = (const float*)d_in[0];
  const float* sw1 = (const float*)d_in[1];
  const float* sw2 = (const float*)d_in[2];
  const float* sw3 = (const float*)d_in[3];
  const float* w1  = (const float*)d_in[4];
  const float* w2  = (const float*)d_in[5];
  const float* w3  = (const float*)d_in[6];
  const float* rw  = (const float*)d_in[7];
  float* out = (float*)d_out;
  char* ws = (char*)d_ws;

  int*   counts = (int*)(ws + WS_COUNTS);
  int*   curs   = (int*)(ws + WS_CURS);
  int*   hbase  = (int*)(ws + WS_HBASE);
  int*   tokl   = (int*)(ws + WS_TOKLIST);
  int*   topi   = (int*)(ws + WS_TOPI);
  float* topw   = (float*)(ws + WS_TOPW);
  int*   posarr = (int*)(ws + WS_POS);
  _Float16* xh   = (_Float16*)(ws + WS_XH);
  _Float16* hbuf = (_Float16*)(ws + WS_H);
  _Float16* wt   = (_Float16*)(ws + WS_WT);
  _Float16* ybuf0 = wt + 9 * WTSLOT;   // dead w1t-expert slots during gemm2
  _Float16* ybuf1 = wt + 11 * WTSLOT;

  hipMemsetAsync(ws, 0, 65792, stream);  // counts/curs + tok lists (pad-token safety)

  k_xh<<<TD * DD / 2048, 256, 0, stream>>>(x, xh);
  k_router<<<TD / 4, 256, 0, stream>>>(x, rw, out + (size_t)TD * DD, topi, topw, counts);
  k_offsets<<<1, 64, 0, stream>>>(counts, hbase);
  k_scatter<<<16, 256, 0, stream>>>(topi, curs, tokl, posarr);

  k_tr1<<<dim3(512, 18), 256, 0, stream>>>(sw1, sw2, w1, w2, wt);
  k_gemm1<<<dim3(HH / 128, 144), 256, 0, stream>>>(xh, wt, counts, hbase, tokl, hbuf);
  k_tr2<<<dim3(512, 9), 256, 0, stream>>>(sw3, w3, wt);
  k_gemm2<<<dim3(DD / 128, 144, 2), 256, 0, stream>>>(hbuf, wt, counts, hbase, ybuf0, ybuf1);
  k_combine<<<TD, 256, 0, stream>>>(ybuf0, ybuf1, topi, topw, posarr, hbase, out);
}